// Round 9
// baseline (1823.338 us; speedup 1.0000x reference)
//
#include <hip/hip_runtime.h>
#include <hip/hip_fp16.h>
#include <math.h>

#define HDIM 2048
#define G4   (4 * HDIM)   // 8192 gate rows
#define NBLK 128          // persistent grid
#define TPB  512          // threads per block (8 waves)
#define NSLOT 1024        // h slots per buffer (2 fp16 per slot)

// __builtin_amdgcn_cvt_pkrtz / __builtin_amdgcn_fdot2 use the __fp16 vector
// type (NOT _Float16 — they don't implicitly convert).
typedef __fp16 h2_t __attribute__((ext_vector_type(2)));

__device__ __forceinline__ float fast_sigmoid(float x) {
    return 1.0f / (1.0f + __expf(-x));
}
__device__ __forceinline__ float fast_tanh(float x) {
    return 1.0f - 2.0f / (1.0f + __expf(2.0f * x));
}
__device__ __forceinline__ h2_t pk2(float a, float b) {
#if __has_builtin(__builtin_amdgcn_cvt_pkrtz)
    return __builtin_amdgcn_cvt_pkrtz(a, b);
#else
    return h2_t{(__fp16)a, (__fp16)b};
#endif
}

// ---------------------------------------------------------------------------
// prep: zero the tagged slot buffers (tag 0 = invalid).
// ---------------------------------------------------------------------------
__global__ __launch_bounds__(256) void prep_slots(unsigned long long* __restrict__ slots) {
    int i = blockIdx.x * blockDim.x + threadIdx.x;
    if (i < 2 * NSLOT) slots[i] = 0ull;
}

// ---------------------------------------------------------------------------
// Fallback-path kernels (round-2 proven pipeline), used only if the
// cooperative launch is rejected.
// ---------------------------------------------------------------------------
__global__ __launch_bounds__(256) void prep_small(const float* __restrict__ bih,
                                                  const float* __restrict__ bhh,
                                                  float* __restrict__ bsum,
                                                  float* __restrict__ c) {
    int i = blockIdx.x * blockDim.x + threadIdx.x;
    if (i < G4) bsum[i] = bih[i] + bhh[i];
    if (i < HDIM) c[i] = 0.0f;
}

__global__ __launch_bounds__(256) void prep_wsum_h(const float* __restrict__ Wih,
                                                   const float* __restrict__ Whh,
                                                   __half* __restrict__ Wsum) {
    const int n8 = (G4 * HDIM) / 8;
    int idx = blockIdx.x * blockDim.x + threadIdx.x;
    int stride = gridDim.x * blockDim.x;
    const float4* a = (const float4*)Wih;
    const float4* b = (const float4*)Whh;
    for (int i = idx; i < n8; i += stride) {
        float4 a0 = a[2 * i], a1 = a[2 * i + 1];
        float4 b0 = b[2 * i], b1 = b[2 * i + 1];
        __half h[8];
        h[0] = __float2half(a0.x + b0.x);
        h[1] = __float2half(a0.y + b0.y);
        h[2] = __float2half(a0.z + b0.z);
        h[3] = __float2half(a0.w + b0.w);
        h[4] = __float2half(a1.x + b1.x);
        h[5] = __float2half(a1.y + b1.y);
        h[6] = __float2half(a1.z + b1.z);
        h[7] = __float2half(a1.w + b1.w);
        ((uint4*)Wsum)[i] = *(const uint4*)h;
    }
}

__global__ __launch_bounds__(256) void lstm_step_f32(const float* __restrict__ x,
                                                     const float* __restrict__ W,
                                                     const float* __restrict__ bsum,
                                                     float* __restrict__ c,
                                                     float* __restrict__ h_out) {
    __shared__ float gates[4][8];
    const int tid  = threadIdx.x;
    const int wave = tid >> 6;
    const int lane = tid & 63;
    const int j0   = blockIdx.x * 8;

    float4 xv[8];
    const float4* xp = (const float4*)x;
#pragma unroll
    for (int k = 0; k < 8; ++k) xv[k] = xp[lane + 64 * k];

    float acc[8];
#pragma unroll
    for (int j8 = 0; j8 < 8; ++j8) {
        const int R = wave * HDIM + j0 + j8;
        const float4* wr = (const float4*)(W + (size_t)R * HDIM);
        float a = 0.0f;
#pragma unroll
        for (int k = 0; k < 8; ++k) {
            float4 wv = wr[lane + 64 * k];
            a += wv.x * xv[k].x + wv.y * xv[k].y + wv.z * xv[k].z + wv.w * xv[k].w;
        }
        acc[j8] = a;
    }
#pragma unroll
    for (int j8 = 0; j8 < 8; ++j8) {
        float a = acc[j8];
#pragma unroll
        for (int off = 32; off > 0; off >>= 1) a += __shfl_down(a, off, 64);
        if (lane == 0) gates[wave][j8] = a + bsum[wave * HDIM + j0 + j8];
    }
    __syncthreads();
    if (tid < 8) {
        const int j = j0 + tid;
        const float si = 1.0f / (1.0f + expf(-gates[0][tid]));
        const float so = 1.0f / (1.0f + expf(-gates[3][tid]));
        const float tg = tanhf(gates[2][tid]);
        const float cn = si * tg;  // c0 = 0
        c[j]     = cn;
        h_out[j] = so * tanhf(cn);
    }
}

__global__ __launch_bounds__(256) void lstm_step_h(const float* __restrict__ x,
                                                   const __half* __restrict__ W,
                                                   const float* __restrict__ bsum,
                                                   float* __restrict__ c,
                                                   float* __restrict__ h_out) {
    __shared__ float gates[4][8];
    const int tid  = threadIdx.x;
    const int wave = tid >> 6;
    const int lane = tid & 63;
    const int j0   = blockIdx.x * 8;

    float xv[32];
    const float4* xp = (const float4*)x;
#pragma unroll
    for (int k = 0; k < 4; ++k) {
        float4 a = xp[k * 128 + lane * 2];
        float4 b = xp[k * 128 + lane * 2 + 1];
        xv[k * 8 + 0] = a.x; xv[k * 8 + 1] = a.y; xv[k * 8 + 2] = a.z; xv[k * 8 + 3] = a.w;
        xv[k * 8 + 4] = b.x; xv[k * 8 + 5] = b.y; xv[k * 8 + 6] = b.z; xv[k * 8 + 7] = b.w;
    }
    float acc[8];
#pragma unroll
    for (int j8 = 0; j8 < 8; ++j8) {
        const int R = wave * HDIM + j0 + j8;
        const uint4* wr = (const uint4*)(W + (size_t)R * HDIM);
        float a = 0.0f;
#pragma unroll
        for (int k = 0; k < 4; ++k) {
            uint4 wv = wr[k * 64 + lane];
            const __half* hh = (const __half*)&wv;
#pragma unroll
            for (int e = 0; e < 8; ++e)
                a = fmaf(__half2float(hh[e]), xv[k * 8 + e], a);
        }
        acc[j8] = a;
    }
#pragma unroll
    for (int j8 = 0; j8 < 8; ++j8) {
        float a = acc[j8];
#pragma unroll
        for (int off = 32; off > 0; off >>= 1) a += __shfl_down(a, off, 64);
        if (lane == 0) gates[wave][j8] = a + bsum[wave * HDIM + j0 + j8];
    }
    __syncthreads();
    if (tid < 8) {
        const int j = j0 + tid;
        const float si = 1.0f / (1.0f + expf(-gates[0][tid]));
        const float sf = 1.0f / (1.0f + expf(-gates[1][tid]));
        const float so = 1.0f / (1.0f + expf(-gates[3][tid]));
        const float tg = tanhf(gates[2][tid]);
        const float cn = sf * c[j] + si * tg;
        c[j]     = cn;
        h_out[j] = so * tanhf(cn);
    }
}

// ---------------------------------------------------------------------------
// Self-contained persistent kernel (weight convert + step 0 + steps 1..T-1).
// 128 blocks x 512 threads. Wave w owns h {16b+2w, 16b+2w+1}, all 4 gates
// (8 rows, 128 fp16-weight VGPRs/lane).
//
// Publish path (NEW, r9): no block barrier. Each wave's lane0 stores ONE
// tagged 8-B word {tag,h2} to LDS (ds_write_b64, atomic). Wave 0 lanes 0-7
// spin on ds_read_b64 until all 8 tags match, then issue the block's slot
// publish as one contiguous 64-B agent-scope burst AND the out[] row as one
// coalesced 64-B wave store (fixes r8's 10x write amplification from
// 8-wave scattered float2 stores). Waves 1-7 proceed directly to the next
// global poll. out[] holds the fp16-rounded h — identical to what the
// recurrence itself consumes.
// ---------------------------------------------------------------------------
__global__ __launch_bounds__(TPB, 2) void lstm_persist(const float* __restrict__ X,
                                                       const float* __restrict__ Wih,
                                                       const float* __restrict__ Whh,
                                                       const float* __restrict__ bih,
                                                       const float* __restrict__ bhh,
                                                       float* __restrict__ out,
                                                       unsigned long long* __restrict__ slots,
                                                       int T) {
    const int tid  = threadIdx.x;
    const int wave = tid >> 6;        // 0..7
    const int lane = tid & 63;
    const int jA   = blockIdx.x * 16 + 2 * wave;  // wave's h indices jA, jA+1

    __shared__ __align__(16) unsigned lds_x[2][NSLOT];  // double-buffered h pairs
    __shared__ unsigned long long h_tag[8];             // per-wave {tag, h2}

    // Init LDS tags BEFORE the long prologue; barrier ensures no wave's
    // later h_tag write can be clobbered by this init.
    if (tid < 8) h_tag[tid] = 0ull;
    __syncthreads();

    if (wave == 0) __builtin_amdgcn_s_setprio(1);  // publisher wave priority

    // ---- X columns for this lane (e-major, matches weight layout) ----
    float xv[32];
    {
        const float4* xp = (const float4*)X;
#pragma unroll
        for (int e = 0; e < 4; ++e) {
            float4 a = xp[(lane + 64 * e) * 2];
            float4 b = xp[(lane + 64 * e) * 2 + 1];
            xv[e * 8 + 0] = a.x; xv[e * 8 + 1] = a.y; xv[e * 8 + 2] = a.z; xv[e * 8 + 3] = a.w;
            xv[e * 8 + 4] = b.x; xv[e * 8 + 5] = b.y; xv[e * 8 + 6] = b.z; xv[e * 8 + 7] = b.w;
        }
    }

    // ---- weight convert + step-0 dot, fused ----
    uint4 w[8][4];
    float bias[8], acc[8];
#pragma unroll
    for (int g = 0; g < 4; ++g)
#pragma unroll
        for (int q = 0; q < 2; ++q) {
            const int j8 = g * 2 + q;
            const size_t R = (size_t)g * HDIM + jA + q;
            const float4* ri = (const float4*)(Wih + R * HDIM);
            const float4* rh = (const float4*)(Whh + R * HDIM);
            float a0acc = 0.0f;
#pragma unroll
            for (int e = 0; e < 4; ++e) {
                float4 a0 = ri[(lane + 64 * e) * 2];
                float4 a1 = ri[(lane + 64 * e) * 2 + 1];
                float4 b0 = rh[(lane + 64 * e) * 2];
                float4 b1 = rh[(lane + 64 * e) * 2 + 1];
                a0acc += a0.x * xv[e * 8 + 0] + a0.y * xv[e * 8 + 1]
                       + a0.z * xv[e * 8 + 2] + a0.w * xv[e * 8 + 3]
                       + a1.x * xv[e * 8 + 4] + a1.y * xv[e * 8 + 5]
                       + a1.z * xv[e * 8 + 6] + a1.w * xv[e * 8 + 7];
                h2_t p0 = pk2(a0.x + b0.x, a0.y + b0.y);
                h2_t p1 = pk2(a0.z + b0.z, a0.w + b0.w);
                h2_t p2 = pk2(a1.x + b1.x, a1.y + b1.y);
                h2_t p3 = pk2(a1.z + b1.z, a1.w + b1.w);
                w[j8][e] = make_uint4(__builtin_bit_cast(unsigned, p0),
                                      __builtin_bit_cast(unsigned, p1),
                                      __builtin_bit_cast(unsigned, p2),
                                      __builtin_bit_cast(unsigned, p3));
            }
            acc[j8]  = a0acc;
            bias[j8] = bih[R] + bhh[R];
        }

    float cA = 0.0f, cB = 0.0f;

    // ================= one step's tail: reduce/pointwise/publish ==========
    // (expressed inline for step 0, then looped for t = 1..T-1)
#define LSTM_TAIL(ACC, TNEXT, OUTROW)                                          \
    {                                                                          \
        _Pragma("unroll")                                                      \
        for (int j8 = 0; j8 < 8; ++j8)                                         \
            _Pragma("unroll")                                                  \
            for (int off = 32; off > 0; off >>= 1)                             \
                ACC[j8] += __shfl_xor(ACC[j8], off, 64);                       \
        const float iA = fast_sigmoid(ACC[0] + bias[0]);                       \
        const float iB = fast_sigmoid(ACC[1] + bias[1]);                       \
        const float fA = fast_sigmoid(ACC[2] + bias[2]);                       \
        const float fB = fast_sigmoid(ACC[3] + bias[3]);                       \
        const float gA = fast_tanh(ACC[4] + bias[4]);                          \
        const float gB = fast_tanh(ACC[5] + bias[5]);                          \
        const float oA = fast_sigmoid(ACC[6] + bias[6]);                       \
        const float oB = fast_sigmoid(ACC[7] + bias[7]);                       \
        cA = fA * cA + iA * gA;                                                \
        cB = fB * cB + iB * gB;                                                \
        const float hA = oA * fast_tanh(cA);                                   \
        const float hB = oB * fast_tanh(cB);                                   \
        if (lane == 0) {                                                       \
            unsigned long long pkv =                                           \
                ((unsigned long long)(unsigned)(TNEXT) << 32)                  \
              | (unsigned long long)__builtin_bit_cast(unsigned, pk2(hA, hB)); \
            __hip_atomic_store(&h_tag[wave], pkv, __ATOMIC_RELAXED,            \
                               __HIP_MEMORY_SCOPE_WORKGROUP);                  \
        }                                                                      \
        if (wave == 0 && lane < 8) {                                           \
            unsigned long long v = __hip_atomic_load(&h_tag[lane],             \
                __ATOMIC_RELAXED, __HIP_MEMORY_SCOPE_WORKGROUP);               \
            while ((unsigned)(v >> 32) != (unsigned)(TNEXT))                   \
                v = __hip_atomic_load(&h_tag[lane], __ATOMIC_RELAXED,          \
                                      __HIP_MEMORY_SCOPE_WORKGROUP);           \
            __hip_atomic_store(                                                \
                &slots[(size_t)((TNEXT) & 1 ^ 1) * 0 /*placeholder*/           \
                       + (size_t)(((TNEXT) - 1) & 1) * NSLOT                   \
                       + blockIdx.x * 8 + lane],                               \
                v, __ATOMIC_RELAXED, __HIP_MEMORY_SCOPE_AGENT);                \
            h2_t hh = __builtin_bit_cast(h2_t, (unsigned)v);                   \
            *(float2*)&out[(size_t)(OUTROW) * HDIM + blockIdx.x * 16 + 2 * lane] \
                = make_float2((float)hh[0], (float)hh[1]);                     \
        }                                                                      \
    }

    // ---- step 0: tag 1 goes into buf 0 ----
    LSTM_TAIL(acc, 1, 0)

    // ---- steps 1..T-1 ----
    for (int t = 1; t < T; ++t) {
        const int buf = (t - 1) & 1;
        const unsigned long long* sl = slots + (size_t)buf * NSLOT;
        const unsigned tg = (unsigned)t;
        const int s0 = wave * 128 + lane;
        const int s1 = s0 + 64;
        unsigned long long v0 = __hip_atomic_load(&sl[s0], __ATOMIC_RELAXED,
                                                  __HIP_MEMORY_SCOPE_AGENT);
        unsigned long long v1 = __hip_atomic_load(&sl[s1], __ATOMIC_RELAXED,
                                                  __HIP_MEMORY_SCOPE_AGENT);
        int spin = 0;
        while (((unsigned)(v0 >> 32) != tg) | ((unsigned)(v1 >> 32) != tg)) {
            if (spin++ > 2) __builtin_amdgcn_s_sleep(1);  // immediate first retries
            if ((unsigned)(v0 >> 32) != tg)
                v0 = __hip_atomic_load(&sl[s0], __ATOMIC_RELAXED,
                                       __HIP_MEMORY_SCOPE_AGENT);
            if ((unsigned)(v1 >> 32) != tg)
                v1 = __hip_atomic_load(&sl[s1], __ATOMIC_RELAXED,
                                       __HIP_MEMORY_SCOPE_AGENT);
        }
        lds_x[buf][s0] = (unsigned)v0;
        lds_x[buf][s1] = (unsigned)v1;
        __syncthreads();  // the only block barrier per step

        // dot: 8 rows x 32 cols per lane
        float a2[8] = {0.f, 0.f, 0.f, 0.f, 0.f, 0.f, 0.f, 0.f};
#pragma unroll
        for (int e = 0; e < 4; ++e) {
            const uint4 xq = *(const uint4*)&lds_x[buf][(lane + 64 * e) * 4];
            const unsigned xs[4] = {xq.x, xq.y, xq.z, xq.w};
#pragma unroll
            for (int p = 0; p < 4; ++p) {
                const h2_t xh = __builtin_bit_cast(h2_t, xs[p]);
#pragma unroll
                for (int j8 = 0; j8 < 8; ++j8) {
                    const h2_t* wh = (const h2_t*)&w[j8][e];
#if __has_builtin(__builtin_amdgcn_fdot2)
                    a2[j8] = __builtin_amdgcn_fdot2(wh[p], xh, a2[j8], false);
#else
                    a2[j8] = fmaf((float)wh[p][0], (float)xh[0],
                                  fmaf((float)wh[p][1], (float)xh[1], a2[j8]));
#endif
                }
            }
        }

        // tag t+1 goes into buf t&1 == ((t+1)-1)&1 — handled inside the macro
        LSTM_TAIL(a2, t + 1, t)
    }
#undef LSTM_TAIL
}

// ---------------------------------------------------------------------------
extern "C" void kernel_launch(void* const* d_in, const int* in_sizes, int n_in,
                              void* d_out, int out_size, void* d_ws, size_t ws_size,
                              hipStream_t stream) {
    const float* X   = (const float*)d_in[0];
    const float* Wih = (const float*)d_in[1];
    const float* Whh = (const float*)d_in[2];
    const float* bih = (const float*)d_in[3];
    const float* bhh = (const float*)d_in[4];
    float* out = (float*)d_out;

    int T = out_size / HDIM;  // 512

    // ws layout (shared with fallback): [Wsum fp16 33.55MB][bsum][c][slots]
    const size_t wsum_bytes = (size_t)G4 * HDIM * sizeof(__half);
    char* ws = (char*)d_ws;
    __half* Wsum = (__half*)ws;
    float*  bsum = (float*)(ws + wsum_bytes);
    float*  c    = bsum + G4;
    unsigned long long* slots = (unsigned long long*)(c + HDIM);

    prep_slots<<<8, 256, 0, stream>>>(slots);

    // Single self-contained persistent kernel (weight convert + all T steps).
    void* args[] = {(void*)&X, (void*)&Wih, (void*)&Whh, (void*)&bih,
                    (void*)&bhh, (void*)&out, (void*)&slots, (void*)&T};
    hipError_t err = hipLaunchCooperativeKernel((const void*)lstm_persist,
                                                dim3(NBLK), dim3(TPB), args, 0, stream);
    if (err != hipSuccess) {
        // Fallback: proven round-2 pipeline.
        prep_small<<<(G4 + 255) / 256, 256, 0, stream>>>(bih, bhh, bsum, c);
        prep_wsum_h<<<2048, 256, 0, stream>>>(Wih, Whh, Wsum);
        lstm_step_f32<<<256, 256, 0, stream>>>(X, Wih, bsum, c, out);
        for (int t = 1; t < T; ++t) {
            const float* hprev = out + (size_t)(t - 1) * HDIM;
            float* hnext = out + (size_t)t * HDIM;
            lstm_step_h<<<256, 256, 0, stream>>>(hprev, Wsum, bsum, c, hnext);
        }
    }
}